// Round 1
// baseline (711.771 us; speedup 1.0000x reference)
//
#include <hip/hip_runtime.h>

#define B_TOTAL 131072
#define XD 45
#define XC 10
#define GD 20
#define PD 200
#define KAPPA 0.8f
#define LAMDA 0.9999f
#define YITA 0.5f

#define MS_KS 216   // M LDS k-stride in elems (27 16B slots, odd -> good banks)
#define PB_KS 208   // p LDS k-stride in elems (k 0..207, pad 200..207 = 0)
#define HB_RS 72    // hebb LDS row-stride (9 slots, odd)

typedef short short8 __attribute__((ext_vector_type(8)));
typedef short short4v __attribute__((ext_vector_type(4)));
typedef float f32x16 __attribute__((ext_vector_type(16)));

__device__ __forceinline__ float bf2f(unsigned short h) {
  union { unsigned int u; float f; } v; v.u = ((unsigned int)h) << 16; return v.f;
}
__device__ __forceinline__ unsigned short f2bf(float f) {
  union { float f; unsigned int u; } v; v.f = f;
  unsigned int r = v.u + 0x7FFFu + ((v.u >> 16) & 1u);
  return (unsigned short)(r >> 16);
}
__device__ __forceinline__ float fp_nl(float v) {  // clip(leaky_relu(v), -1, 1)
  v = (v > 0.f) ? v : 0.01f * v;
  return fminf(1.f, fmaxf(-1.f, v));
}

__global__ void tem_init_m(const float* __restrict__ Min, float* __restrict__ oM) {
  int i = blockIdx.x * 256 + threadIdx.x;
  if (i < PD * PD) oM[i] = LAMDA * Min[i];
}

__global__ __launch_bounds__(256, 1) void tem_main(
    const float* __restrict__ xin, const float* __restrict__ gin,
    const float* __restrict__ Min, const float* __restrict__ Wc,
    const float* __restrict__ W1ie, const float* __restrict__ b1ie,
    const float* __restrict__ W2ie, const float* __restrict__ b2ie,
    const float* __restrict__ W1gg, const float* __restrict__ b1gg,
    const float* __restrict__ W2gg, const float* __restrict__ b2gg,
    const float* __restrict__ Wsp, const float* __restrict__ bsp,
    float* __restrict__ o_ginf, float* __restrict__ o_xinf,
    float* __restrict__ o_g, float* __restrict__ o_x,
    unsigned short* __restrict__ dW, unsigned short* __restrict__ sW) {
  // LDS: 96768 + 53248 + 2560 + 10240 = 162816 B (<= 163840)
  __shared__ __attribute__((aligned(16))) unsigned short Ms[224 * MS_KS];
  __shared__ __attribute__((aligned(16))) unsigned short Pb[4 * 32 * PB_KS];
  __shared__ unsigned short xcS[128 * 10];
  __shared__ float g2S[128 * 20];

  const int tid = threadIdx.x;
  const int lane = tid & 63;
  const int wid = tid >> 6;
  const int cl = lane & 31;
  const int hi = lane >> 5;

  // ---- Stage M^T (+ kappa*I on diagonal) as bf16, zero-padded to [224][216]
  for (int i = tid; i < 224 * MS_KS; i += 256) Ms[i] = 0;
  __syncthreads();
  for (int i = tid; i < 200 * 224; i += 256) {
    const int k = i / 224, n = i - k * 224;
    if (n < 200) {
      float v = Min[k * 200 + n];
      if (k == n) v += KAPPA;
      Ms[n * MS_KS + k] = f2bf(v);
    }
  }
  __syncthreads();

  for (int chunk = 0; chunk < 4; ++chunk) {
    const int r0 = (blockIdx.x * 4 + chunk) * 128;

    // ---- P0: per-row prologue (threads 0..127: g2 MLP; 128..255: xc)
    if (tid < 128) {
      const int r = r0 + tid;
      float gv[20];
#pragma unroll
      for (int i = 0; i < 20; ++i) gv[i] = gin[(size_t)r * 20 + i];
      float h[40];
#pragma unroll
      for (int u = 0; u < 40; ++u) h[u] = b1gg[u];
      for (int i = 0; i < 20; ++i)
#pragma unroll
        for (int u = 0; u < 40; ++u) h[u] += gv[i] * W1gg[i * 40 + u];
#pragma unroll
      for (int u = 0; u < 40; ++u) h[u] = (h[u] > 0.f) ? h[u] : (expf(h[u]) - 1.f);
      for (int o = 0; o < 20; ++o) {
        float v = b2gg[o];
#pragma unroll
        for (int u = 0; u < 40; ++u) v += h[u] * W2gg[u * 20 + o];
        g2S[tid * 20 + o] = tanhf(v);
      }
    } else {
      const int rr = tid - 128;
      const int r = r0 + rr;
      float xc[10];
#pragma unroll
      for (int o = 0; o < 10; ++o) xc[o] = 0.f;
      for (int j = 0; j < XD; ++j) {
        const float xv = xin[(size_t)r * XD + j];
#pragma unroll
        for (int o = 0; o < 10; ++o) xc[o] += xv * Wc[j * 10 + o];
      }
#pragma unroll
      for (int o = 0; o < 10; ++o) xcS[rr * 10 + o] = f2bf(xc[o]);
    }
    __syncthreads();

    // ---- P1: write g_ and x_ outputs (f32)
    for (int i = tid; i < 128 * 200; i += 256) {
      const int r = i / 200, j = i - r * 200;
      o_g[(size_t)(r0 + r) * 200 + j] = g2S[r * 20 + j / 10];
      o_x[(size_t)(r0 + r) * 200 + j] = bf2f(xcS[r * 10 + (j % 10)]);
    }

    // ---- two retrievals
    for (int ret = 0; ret < 2; ++ret) {
      unsigned short* pW = Pb + wid * (32 * PB_KS);
      // init p0 (x_ tiled for ret 0, g_ repeated for ret 1); zero k-pad
      for (int i = lane; i < 32 * PB_KS; i += 64) {
        const int rr = i / PB_KS, k = i - rr * PB_KS;
        float v = 0.f;
        if (k < 200) {
          if (ret == 0) v = bf2f(xcS[(wid * 32 + rr) * 10 + (k % 10)]);
          else          v = g2S[(wid * 32 + rr) * 20 + (k / 10)];
        }
        pW[i] = f2bf(v);
      }
      __syncthreads();

      for (int it = 0; it < 5; ++it) {
        f32x16 acc[7];
#pragma unroll
        for (int nt = 0; nt < 7; ++nt)
#pragma unroll
          for (int q = 0; q < 16; ++q) acc[nt][q] = 0.f;
#pragma unroll
        for (int kc = 0; kc < 13; ++kc) {
          const short8 af = *(const short8*)(pW + (cl * PB_KS + kc * 16 + hi * 8));
#pragma unroll
          for (int nt = 0; nt < 7; ++nt) {
            const short8 bfr = *(const short8*)(Ms + ((nt * 32 + cl) * MS_KS + kc * 16 + hi * 8));
            acc[nt] = __builtin_amdgcn_mfma_f32_32x32x16_bf16(af, bfr, acc[nt], 0, 0, 0);
          }
        }
        // nonlinearity + writeback (k-pad 200..207 stays zero)
#pragma unroll
        for (int nt = 0; nt < 7; ++nt) {
          const int n = nt * 32 + cl;
          if (n < 200) {
#pragma unroll
            for (int rg = 0; rg < 16; ++rg) {
              const int row = (rg & 3) + 8 * (rg >> 2) + 4 * hi;
              pW[row * PB_KS + n] = f2bf(fp_nl(acc[nt][rg]));
            }
          }
        }
        __syncthreads();
      }

      if (ret == 0) {
        // ---- E1: g_inf = clip(MLP(px @ W_repeat^T))
        const int r = tid >> 1, half = tid & 1;
        const unsigned short* prow = Pb + (r >> 5) * (32 * PB_KS) + (r & 31) * PB_KS;
        float pxg[10];
#pragma unroll
        for (int gi = 0; gi < 10; ++gi) {
          const int g0 = (half * 10 + gi) * 10;
          float s = 0.f;
#pragma unroll
          for (int u = 0; u < 10; ++u) s += bf2f(prow[g0 + u]);
          pxg[gi] = s;
        }
        float pxgF[20];
#pragma unroll
        for (int gi = 0; gi < 10; ++gi) {
          const float oth = __shfl_xor(pxg[gi], 1);
          pxgF[half * 10 + gi] = pxg[gi];
          pxgF[(1 - half) * 10 + gi] = oth;
        }
        float e[20];
#pragma unroll
        for (int j = 0; j < 20; ++j) {
          const int u = half * 20 + j;
          float hv = b1ie[u];
          for (int gg = 0; gg < 20; ++gg) hv += pxgF[gg] * W1ie[gg * 40 + u];
          e[j] = (hv > 0.f) ? hv : (expf(hv) - 1.f);
        }
        float eO[20];
#pragma unroll
        for (int j = 0; j < 20; ++j) eO[j] = __shfl_xor(e[j], 1);
#pragma unroll
        for (int oi = 0; oi < 10; ++oi) {
          const int o = half * 10 + oi;
          float v = b2ie[o];
          for (int j = 0; j < 20; ++j) {
            v += e[j]  * W2ie[(half * 20 + j) * 20 + o];
            v += eO[j] * W2ie[((1 - half) * 20 + j) * 20 + o];
          }
          v = fminf(1.f, fmaxf(-1.f, v));
          o_ginf[(size_t)(r0 + r) * 20 + o] = v;
        }
      } else {
        // ---- E2: x_inf, and d/s for hebb
        {
          const int r = tid >> 1, half = tid & 1;
          const unsigned short* prow = Pb + (r >> 5) * (32 * PB_KS) + (r & 31) * PB_KS;
          float ta[5];
#pragma unroll
          for (int a = 0; a < 5; ++a) {
            const int aa = half * 5 + a;
            float s = 0.f;
#pragma unroll
            for (int j = 0; j < 20; ++j) s += bf2f(prow[aa + 10 * j]);
            ta[a] = s;
          }
          float taF[10];
#pragma unroll
          for (int a = 0; a < 5; ++a) {
            const float oth = __shfl_xor(ta[a], 1);
            taF[half * 5 + a] = ta[a];
            taF[(1 - half) * 5 + a] = oth;
          }
          const int o0 = half ? 23 : 0, o1 = half ? 45 : 23;
          for (int o = o0; o < o1; ++o) {
            float v = bsp[o];
#pragma unroll
            for (int a = 0; a < 10; ++a) v += taF[a] * Wsp[a * 45 + o];
            o_xinf[(size_t)(r0 + r) * 45 + o] = v;
          }
        }
        {
          unsigned int* dW32 = (unsigned int*)dW;
          unsigned int* sW32 = (unsigned int*)sW;
          for (int i = tid; i < 128 * 100; i += 256) {
            const int r = i / 100, jp = i - r * 100;
            const int j0 = jp * 2;
            const unsigned short* prow = Pb + (r >> 5) * (32 * PB_KS) + (r & 31) * PB_KS;
            unsigned int dpack = 0, spack = 0;
#pragma unroll
            for (int q = 0; q < 2; ++q) {
              const int j = j0 + q;
              const float pv = bf2f(prow[j]);
              const float xv = bf2f(xcS[r * 10 + (j % 10)]);
              const float gv = g2S[r * 20 + (j / 10)];
              const float pi = fp_nl(gv * xv);
              dpack |= ((unsigned int)f2bf(pi - pv)) << (16 * q);
              spack |= ((unsigned int)f2bf(pi + pv)) << (16 * q);
            }
            const size_t idx = ((size_t)(r0 + r) * 200 + j0) >> 1;
            dW32[idx] = dpack;
            sW32[idx] = spack;
          }
        }
      }
      __syncthreads();
    }
  }
}

__global__ __launch_bounds__(448, 1) void tem_hebb(
    const unsigned short* __restrict__ dW, const unsigned short* __restrict__ sW,
    float* __restrict__ oM) {
  __shared__ __attribute__((aligned(16))) unsigned short dT[224 * HB_RS];
  __shared__ __attribute__((aligned(16))) unsigned short sT[224 * HB_RS];
  const int tid = threadIdx.x;
  const int lane = tid & 63, wid = tid >> 6;
  const int cl = lane & 31, hi = lane >> 5;
  for (int i = tid; i < 224 * HB_RS; i += 448) { dT[i] = 0; sT[i] = 0; }
  f32x16 hacc[7];
#pragma unroll
  for (int nt = 0; nt < 7; ++nt)
#pragma unroll
    for (int q = 0; q < 16; ++q) hacc[nt][q] = 0.f;
  const int kbase = blockIdx.x * 1024;
  for (int sub = 0; sub < 16; ++sub) {
    __syncthreads();
    const int kb = kbase + sub * 64;
    for (int i = tid; i < 64 * 50; i += 448) {
      const int rr = i / 50, fq = i - rr * 50;
      const int f0 = fq * 4;
      const short4v d4 = *(const short4v*)(dW + ((size_t)(kb + rr) * 200 + f0));
      const short4v s4 = *(const short4v*)(sW + ((size_t)(kb + rr) * 200 + f0));
#pragma unroll
      for (int q = 0; q < 4; ++q) {
        dT[(f0 + q) * HB_RS + rr] = (unsigned short)d4[q];
        sT[(f0 + q) * HB_RS + rr] = (unsigned short)s4[q];
      }
    }
    __syncthreads();
#pragma unroll
    for (int kc = 0; kc < 4; ++kc) {
      const short8 af = *(const short8*)(dT + ((wid * 32 + cl) * HB_RS + kc * 16 + hi * 8));
#pragma unroll
      for (int nt = 0; nt < 7; ++nt) {
        const short8 bfr = *(const short8*)(sT + ((nt * 32 + cl) * HB_RS + kc * 16 + hi * 8));
        hacc[nt] = __builtin_amdgcn_mfma_f32_32x32x16_bf16(af, bfr, hacc[nt], 0, 0, 0);
      }
    }
  }
  const float scale = YITA / (float)B_TOTAL;
#pragma unroll
  for (int nt = 0; nt < 7; ++nt) {
    const int j = nt * 32 + cl;
    if (j < 200) {
#pragma unroll
      for (int rg = 0; rg < 16; ++rg) {
        const int ii = wid * 32 + (rg & 3) + 8 * (rg >> 2) + 4 * hi;
        if (ii < 200) atomicAdd(&oM[ii * 200 + j], hacc[nt][rg] * scale);
      }
    }
  }
}

extern "C" void kernel_launch(void* const* d_in, const int* in_sizes, int n_in,
                              void* d_out, int out_size, void* d_ws, size_t ws_size,
                              hipStream_t stream) {
  (void)in_sizes; (void)n_in; (void)out_size; (void)ws_size;
  const float* xin  = (const float*)d_in[0];
  const float* gin  = (const float*)d_in[1];
  const float* Min  = (const float*)d_in[2];
  const float* Wc   = (const float*)d_in[3];
  const float* W1ie = (const float*)d_in[4];
  const float* b1ie = (const float*)d_in[5];
  const float* W2ie = (const float*)d_in[6];
  const float* b2ie = (const float*)d_in[7];
  const float* W1gg = (const float*)d_in[8];
  const float* b1gg = (const float*)d_in[9];
  const float* W2gg = (const float*)d_in[10];
  const float* b2gg = (const float*)d_in[11];
  const float* Wsp  = (const float*)d_in[12];
  const float* bsp  = (const float*)d_in[13];

  float* out = (float*)d_out;
  float* o_ginf = out;
  float* o_xinf = out + (size_t)B_TOTAL * 20;
  float* o_g    = out + (size_t)B_TOTAL * 65;
  float* o_x    = out + (size_t)B_TOTAL * 265;
  float* o_M    = out + (size_t)B_TOTAL * 465;

  unsigned short* dW = (unsigned short*)d_ws;
  unsigned short* sW = dW + (size_t)B_TOTAL * 200;

  tem_init_m<<<(PD * PD + 255) / 256, 256, 0, stream>>>(Min, o_M);
  tem_main<<<256, 256, 0, stream>>>(xin, gin, Min, Wc, W1ie, b1ie, W2ie, b2ie,
                                    W1gg, b1gg, W2gg, b2gg, Wsp, bsp,
                                    o_ginf, o_xinf, o_g, o_x, dW, sW);
  tem_hebb<<<128, 448, 0, stream>>>(dW, sW, o_M);
}